// Round 1
// baseline (2544.095 us; speedup 1.0000x reference)
//
#include <hip/hip_runtime.h>
#include <hip/hip_bf16.h>

// Problem constants (from reference setup_inputs)
#define C_IN  512
#define C_HID 256
#define C_OUT 64
#define K_STEPS 10
#define ALPHA 0.1f

// ---------------------------------------------------------------------------
// Graph preprocessing
// ---------------------------------------------------------------------------

__global__ void k_count(const int* __restrict__ dst, int E, int* __restrict__ counts) {
    int i = blockIdx.x * blockDim.x + threadIdx.x;
    if (i < E) atomicAdd(&counts[dst[i]], 1);
}

__global__ void k_dinv(const int* __restrict__ counts, float* __restrict__ dinv, int N) {
    int i = blockIdx.x * blockDim.x + threadIdx.x;
    if (i < N) {
        float deg = (float)(counts[i] + 1);   // +1 self-loop
        dinv[i] = 1.0f / sqrtf(deg);
    }
}

#define SCAN_CHUNK 2048

__global__ void k_scan1(const int* __restrict__ counts, int N, int* __restrict__ bsum) {
    __shared__ int sdata[256];
    int b = blockIdx.x, t = threadIdx.x;
    int base = b * SCAN_CHUNK;
    int sum = 0;
    for (int i = t; i < SCAN_CHUNK; i += 256) {
        int idx = base + i;
        sum += (idx < N) ? counts[idx] : 0;
    }
    sdata[t] = sum;
    __syncthreads();
    for (int off = 128; off; off >>= 1) {
        if (t < off) sdata[t] += sdata[t + off];
        __syncthreads();
    }
    if (t == 0) bsum[b] = sdata[0];
}

__global__ void k_scan2(int* __restrict__ bsum, int nb, int E, int* __restrict__ rowptr, int N) {
    if (blockIdx.x == 0 && threadIdx.x == 0) {
        int run = 0;
        for (int i = 0; i < nb; i++) { int v = bsum[i]; bsum[i] = run; run += v; }
        rowptr[N] = E;
    }
}

__global__ void k_scan3(const int* __restrict__ counts, int N,
                        const int* __restrict__ bsum, int* __restrict__ rowptr) {
    __shared__ int sdata[256];
    int b = blockIdx.x, t = threadIdx.x;
    int base = b * SCAN_CHUNK;
    int vals[8];
    int local = 0;
    #pragma unroll
    for (int i = 0; i < 8; i++) {
        int idx = base + t * 8 + i;
        vals[i] = (idx < N) ? counts[idx] : 0;
        local += vals[i];
    }
    sdata[t] = local;
    __syncthreads();
    // Hillis-Steele inclusive scan over the 256 per-thread sums
    for (int off = 1; off < 256; off <<= 1) {
        int y = 0;
        if (t >= off) y = sdata[t - off];
        __syncthreads();
        sdata[t] += y;
        __syncthreads();
    }
    int excl = (t == 0) ? 0 : sdata[t - 1];
    int run = bsum[b] + excl;
    #pragma unroll
    for (int i = 0; i < 8; i++) {
        int idx = base + t * 8 + i;
        if (idx < N) rowptr[idx] = run;
        run += vals[i];
    }
}

__global__ void k_fill(const int* __restrict__ src, const int* __restrict__ dst, int E,
                       const float* __restrict__ dinv, int* __restrict__ cursor,
                       int* __restrict__ csr_src, float* __restrict__ csr_norm) {
    int e = blockIdx.x * blockDim.x + threadIdx.x;
    if (e < E) {
        int s = src[e], d = dst[e];
        int p = atomicAdd(&cursor[d], 1);
        csr_src[p] = s;
        csr_norm[p] = dinv[s] * dinv[d];
    }
}

// ---------------------------------------------------------------------------
// MLP: f32 tiled GEMM, C = act(A[MxK] @ B[KxN] + bias)
// BM=BN=64, BK=16, 256 threads, 4x4 per thread
// ---------------------------------------------------------------------------

template <bool RELU>
__global__ void k_gemm(const float* __restrict__ A, const float* __restrict__ B,
                       const float* __restrict__ bias, float* __restrict__ C,
                       int M, int N, int K) {
    __shared__ float As[16][68];   // transposed A tile, padded
    __shared__ float Bs[16][64];
    int t = threadIdx.x;
    int tx = t & 15, ty = t >> 4;
    int bm = blockIdx.x * 64;
    int bn = blockIdx.y * 64;
    float acc[4][4] = {};

    for (int k0 = 0; k0 < K; k0 += 16) {
        {   // A tile: 64 rows x 16 k, one float4 per thread
            int row = t >> 2;
            int col = (t & 3) * 4;
            int gr = bm + row;
            float4 a = make_float4(0.f, 0.f, 0.f, 0.f);
            if (gr < M) a = *(const float4*)&A[(size_t)gr * K + k0 + col];
            As[col + 0][row] = a.x;
            As[col + 1][row] = a.y;
            As[col + 2][row] = a.z;
            As[col + 3][row] = a.w;
        }
        {   // B tile: 16 k x 64 cols, one float4 per thread
            int kk = t >> 4;
            int col = (t & 15) * 4;
            float4 bv = *(const float4*)&B[(size_t)(k0 + kk) * N + bn + col];
            *(float4*)&Bs[kk][col] = bv;
        }
        __syncthreads();
        #pragma unroll
        for (int kk = 0; kk < 16; kk++) {
            float4 a4 = *(const float4*)&As[kk][ty * 4];
            float4 b4 = *(const float4*)&Bs[kk][tx * 4];
            float av[4] = {a4.x, a4.y, a4.z, a4.w};
            float bv[4] = {b4.x, b4.y, b4.z, b4.w};
            #pragma unroll
            for (int mi = 0; mi < 4; mi++)
                #pragma unroll
                for (int ni = 0; ni < 4; ni++)
                    acc[mi][ni] += av[mi] * bv[ni];
        }
        __syncthreads();
    }

    #pragma unroll
    for (int mi = 0; mi < 4; mi++) {
        int gr = bm + ty * 4 + mi;
        if (gr >= M) continue;
        #pragma unroll
        for (int ni = 0; ni < 4; ni++) {
            int gc = bn + tx * 4 + ni;
            float v = acc[mi][ni] + bias[gc];
            if (RELU) v = fmaxf(v, 0.f);
            C[(size_t)gr * N + gc] = v;
        }
    }
}

// ---------------------------------------------------------------------------
// APPNP propagation: one wave per dst node, lane = channel (C_OUT = 64)
// nxt = (1-a) * (selfnorm*cur[node] + sum_e norm[e]*cur[src[e]]) + a*h
// ---------------------------------------------------------------------------

__global__ void k_prop(const int* __restrict__ rowptr, const int* __restrict__ csr_src,
                       const float* __restrict__ csr_norm, const float* __restrict__ dinv,
                       const float* __restrict__ h, const float* __restrict__ cur,
                       float* __restrict__ nxt, int N) {
    int node = blockIdx.x * (blockDim.x >> 6) + (threadIdx.x >> 6);
    int lane = threadIdx.x & 63;
    if (node >= N) return;
    float dn = dinv[node];
    float acc = dn * dn * cur[(size_t)node * C_OUT + lane];
    int beg = rowptr[node], end = rowptr[node + 1];
    int e = beg;
    for (; e + 1 < end; e += 2) {
        int s0 = csr_src[e], s1 = csr_src[e + 1];
        float w0 = csr_norm[e], w1 = csr_norm[e + 1];
        float v0 = cur[(size_t)s0 * C_OUT + lane];
        float v1 = cur[(size_t)s1 * C_OUT + lane];
        acc += w0 * v0;
        acc += w1 * v1;
    }
    if (e < end) {
        int s0 = csr_src[e];
        float w0 = csr_norm[e];
        acc += w0 * cur[(size_t)s0 * C_OUT + lane];
    }
    nxt[(size_t)node * C_OUT + lane] =
        (1.0f - ALPHA) * acc + ALPHA * h[(size_t)node * C_OUT + lane];
}

// ---------------------------------------------------------------------------
// log_softmax over 64 classes: one wave per node
// ---------------------------------------------------------------------------

__global__ void k_logsoftmax(const float* __restrict__ in, float* __restrict__ out, int N) {
    int node = blockIdx.x * (blockDim.x >> 6) + (threadIdx.x >> 6);
    int lane = threadIdx.x & 63;
    if (node >= N) return;
    float v = in[(size_t)node * C_OUT + lane];
    float m = v;
    #pragma unroll
    for (int off = 32; off; off >>= 1) m = fmaxf(m, __shfl_xor(m, off));
    float ex = __expf(v - m);
    float s = ex;
    #pragma unroll
    for (int off = 32; off; off >>= 1) s += __shfl_xor(s, off);
    out[(size_t)node * C_OUT + lane] = v - m - logf(s);
}

// ---------------------------------------------------------------------------
// Launch
// ---------------------------------------------------------------------------

extern "C" void kernel_launch(void* const* d_in, const int* in_sizes, int n_in,
                              void* d_out, int out_size, void* d_ws, size_t ws_size,
                              hipStream_t stream) {
    const float* x  = (const float*)d_in[0];
    const int*   ei = (const int*)d_in[1];
    const float* W1 = (const float*)d_in[2];
    const float* b1 = (const float*)d_in[3];
    const float* W2 = (const float*)d_in[4];
    const float* b2 = (const float*)d_in[5];

    const int N = in_sizes[0] / C_IN;
    const int E = in_sizes[1] / 2;
    const int* src = ei;
    const int* dst = ei + E;

    // workspace bump allocator (256B aligned)
    char* ws = (char*)d_ws;
    size_t off = 0;
    auto alloc = [&](size_t bytes) -> void* {
        void* p = ws + off;
        off += (bytes + 255) & ~(size_t)255;
        return p;
    };

    int nb = (N + SCAN_CHUNK - 1) / SCAN_CHUNK;

    int*   counts   = (int*)  alloc((size_t)4 * N);
    int*   rowptr   = (int*)  alloc((size_t)4 * (N + 1));
    int*   cursor   = (int*)  alloc((size_t)4 * N);
    float* dinv     = (float*)alloc((size_t)4 * N);
    int*   bsum     = (int*)  alloc((size_t)4 * (nb + 1));
    int*   csr_src  = (int*)  alloc((size_t)4 * E);
    float* csr_norm = (float*)alloc((size_t)4 * E);
    float* hmid     = (float*)alloc((size_t)4 * N * C_HID);
    float* h        = (float*)alloc((size_t)4 * N * C_OUT);
    float* buf0     = (float*)alloc((size_t)4 * N * C_OUT);
    float* buf1     = (float*)alloc((size_t)4 * N * C_OUT);

    // --- graph preprocessing ---
    hipMemsetAsync(counts, 0, (size_t)4 * N, stream);
    k_count<<<(E + 255) / 256, 256, 0, stream>>>(dst, E, counts);
    k_dinv<<<(N + 255) / 256, 256, 0, stream>>>(counts, dinv, N);
    k_scan1<<<nb, 256, 0, stream>>>(counts, N, bsum);
    k_scan2<<<1, 64, 0, stream>>>(bsum, nb, E, rowptr, N);
    k_scan3<<<nb, 256, 0, stream>>>(counts, N, bsum, rowptr);
    hipMemcpyAsync(cursor, rowptr, (size_t)4 * N, hipMemcpyDeviceToDevice, stream);
    k_fill<<<(E + 255) / 256, 256, 0, stream>>>(src, dst, E, dinv, cursor, csr_src, csr_norm);

    // --- MLP ---
    {
        dim3 g1((N + 63) / 64, C_HID / 64);
        k_gemm<true><<<g1, 256, 0, stream>>>(x, W1, b1, hmid, N, C_HID, C_IN);
        dim3 g2((N + 63) / 64, C_OUT / 64);
        k_gemm<false><<<g2, 256, 0, stream>>>(hmid, W2, b2, h, N, C_OUT, C_HID);
    }

    // --- propagation (ping-pong; last iter writes d_out) ---
    int nodes_per_block = 256 / 64;
    int pgrid = (N + nodes_per_block - 1) / nodes_per_block;
    const float* cur = h;
    for (int it = 0; it < K_STEPS; ++it) {
        float* nxt = (it == K_STEPS - 1) ? (float*)d_out : ((it & 1) ? buf1 : buf0);
        k_prop<<<pgrid, 256, 0, stream>>>(rowptr, csr_src, csr_norm, dinv, h, cur, nxt, N);
        cur = nxt;
    }

    // --- log_softmax (in-place on d_out) ---
    k_logsoftmax<<<pgrid, 256, 0, stream>>>((const float*)d_out, (float*)d_out, N);
}

// Round 2
// 1686.351 us; speedup vs baseline: 1.5086x; 1.5086x over previous
//
#include <hip/hip_runtime.h>
#include <hip/hip_bf16.h>

#define C_IN  512
#define C_HID 256
#define C_OUT 64
#define K_STEPS 10
#define ALPHA 0.1f

typedef _Float16 half8 __attribute__((ext_vector_type(8)));
typedef float f32x4 __attribute__((ext_vector_type(4)));

// ---------------------------------------------------------------------------
// Graph preprocessing
// ---------------------------------------------------------------------------

__global__ void k_count(const int* __restrict__ dst, int E, int* __restrict__ counts) {
    int i = blockIdx.x * blockDim.x + threadIdx.x;
    if (i < E) atomicAdd(&counts[dst[i]], 1);
}

__global__ void k_dinv(const int* __restrict__ counts, float* __restrict__ dinv, int N) {
    int i = blockIdx.x * blockDim.x + threadIdx.x;
    if (i < N) {
        float deg = (float)(counts[i] + 1);   // +1 self-loop
        dinv[i] = 1.0f / sqrtf(deg);
    }
}

#define SCAN_CHUNK 2048

__global__ void k_scan1(const int* __restrict__ counts, int N, int* __restrict__ bsum) {
    __shared__ int sdata[256];
    int b = blockIdx.x, t = threadIdx.x;
    int base = b * SCAN_CHUNK;
    int sum = 0;
    for (int i = t; i < SCAN_CHUNK; i += 256) {
        int idx = base + i;
        sum += (idx < N) ? counts[idx] : 0;
    }
    sdata[t] = sum;
    __syncthreads();
    for (int off = 128; off; off >>= 1) {
        if (t < off) sdata[t] += sdata[t + off];
        __syncthreads();
    }
    if (t == 0) bsum[b] = sdata[0];
}

__global__ void k_scan2(int* __restrict__ bsum, int nb, int E, int* __restrict__ rowptr, int N) {
    if (blockIdx.x == 0 && threadIdx.x == 0) {
        int run = 0;
        for (int i = 0; i < nb; i++) { int v = bsum[i]; bsum[i] = run; run += v; }
        rowptr[N] = E;
    }
}

__global__ void k_scan3(const int* __restrict__ counts, int N,
                        const int* __restrict__ bsum, int* __restrict__ rowptr) {
    __shared__ int sdata[256];
    int b = blockIdx.x, t = threadIdx.x;
    int base = b * SCAN_CHUNK;
    int vals[8];
    int local = 0;
    #pragma unroll
    for (int i = 0; i < 8; i++) {
        int idx = base + t * 8 + i;
        vals[i] = (idx < N) ? counts[idx] : 0;
        local += vals[i];
    }
    sdata[t] = local;
    __syncthreads();
    for (int off = 1; off < 256; off <<= 1) {
        int y = 0;
        if (t >= off) y = sdata[t - off];
        __syncthreads();
        sdata[t] += y;
        __syncthreads();
    }
    int excl = (t == 0) ? 0 : sdata[t - 1];
    int run = bsum[b] + excl;
    #pragma unroll
    for (int i = 0; i < 8; i++) {
        int idx = base + t * 8 + i;
        if (idx < N) rowptr[idx] = run;
        run += vals[i];
    }
}

__global__ void k_fill(const int* __restrict__ src, const int* __restrict__ dst, int E,
                       const float* __restrict__ dinv, int* __restrict__ cursor,
                       int* __restrict__ csr_src, float* __restrict__ csr_norm) {
    int e = blockIdx.x * blockDim.x + threadIdx.x;
    if (e < E) {
        int s = src[e], d = dst[e];
        int p = atomicAdd(&cursor[d], 1);
        csr_src[p] = s;
        csr_norm[p] = dinv[s] * dinv[d];
    }
}

// ---------------------------------------------------------------------------
// Weight pre-transpose + f16 conversion: W [K][N] f32 -> Wt [N][K] f16
// ---------------------------------------------------------------------------

__global__ void k_w1t(const float* __restrict__ W, _Float16* __restrict__ Wt) {
    int i = blockIdx.x * 256 + threadIdx.x;          // over 512*256
    int k = i >> 8, n = i & 255;
    Wt[(size_t)n * 512 + k] = (_Float16)W[i];
}

__global__ void k_w2t(const float* __restrict__ W, _Float16* __restrict__ Wt) {
    int i = blockIdx.x * 256 + threadIdx.x;          // over 256*64
    int k = i >> 6, n = i & 63;
    Wt[(size_t)n * 256 + k] = (_Float16)W[i];
}

// ---------------------------------------------------------------------------
// MLP layer 1: hmid[M][256] f16 = relu(x[M][512] f32 @ W1 + b1), f16 MFMA
// Block: 256 threads = 4 waves; BM=64 rows, each wave owns 64 cols of 256.
// A frags converted f32->f16 in-reg; B frags loaded direct from W1t (L2-hot).
// ---------------------------------------------------------------------------

__global__ __launch_bounds__(256) void k_mlp1(
    const float* __restrict__ A, const _Float16* __restrict__ Bt,
    const float* __restrict__ bias, _Float16* __restrict__ C, int M)
{
    int lane = threadIdx.x & 63;
    int wid  = threadIdx.x >> 6;
    int bm   = blockIdx.x * 64;
    int n_off = wid * 64;
    int mrow = lane & 15;
    int kg   = lane >> 4;
    f32x4 acc[4][4] = {};

    int r[4];
    #pragma unroll
    for (int mi = 0; mi < 4; mi++) {
        int rr = bm + mi * 16 + mrow;
        r[mi] = rr < M ? rr : M - 1;
    }

    for (int k0 = 0; k0 < 512; k0 += 32) {
        int k = k0 + kg * 8;
        half8 a[4], b[4];
        #pragma unroll
        for (int mi = 0; mi < 4; mi++) {
            const float* p = A + (size_t)r[mi] * 512 + k;
            float4 lo = *(const float4*)p;
            float4 hi = *(const float4*)(p + 4);
            a[mi][0] = (_Float16)lo.x; a[mi][1] = (_Float16)lo.y;
            a[mi][2] = (_Float16)lo.z; a[mi][3] = (_Float16)lo.w;
            a[mi][4] = (_Float16)hi.x; a[mi][5] = (_Float16)hi.y;
            a[mi][6] = (_Float16)hi.z; a[mi][7] = (_Float16)hi.w;
        }
        #pragma unroll
        for (int ni = 0; ni < 4; ni++) {
            int n = n_off + ni * 16 + mrow;
            b[ni] = *(const half8*)(Bt + (size_t)n * 512 + k);
        }
        #pragma unroll
        for (int mi = 0; mi < 4; mi++)
            #pragma unroll
            for (int ni = 0; ni < 4; ni++)
                acc[mi][ni] = __builtin_amdgcn_mfma_f32_16x16x32_f16(
                    a[mi], b[ni], acc[mi][ni], 0, 0, 0);
    }

    #pragma unroll
    for (int mi = 0; mi < 4; mi++) {
        #pragma unroll
        for (int ni = 0; ni < 4; ni++) {
            int n = n_off + ni * 16 + mrow;
            float bv = bias[n];
            #pragma unroll
            for (int rg = 0; rg < 4; rg++) {
                int row = bm + mi * 16 + kg * 4 + rg;
                if (row < M) {
                    float v = acc[mi][ni][rg] + bv;
                    C[(size_t)row * 256 + n] = (_Float16)fmaxf(v, 0.f);
                }
            }
        }
    }
}

// ---------------------------------------------------------------------------
// MLP layer 2: h[M][64] f16 = hmid[M][256] f16 @ W2 + b2, f16 MFMA
// Block: 256 threads = 4 waves; each wave owns 64 rows, all 64 cols.
// ---------------------------------------------------------------------------

__global__ __launch_bounds__(256) void k_mlp2(
    const _Float16* __restrict__ A, const _Float16* __restrict__ Bt,
    const float* __restrict__ bias, _Float16* __restrict__ C, int M)
{
    int lane = threadIdx.x & 63;
    int wid  = threadIdx.x >> 6;
    int bm   = blockIdx.x * 256 + wid * 64;
    int mrow = lane & 15;
    int kg   = lane >> 4;
    f32x4 acc[4][4] = {};

    int r[4];
    #pragma unroll
    for (int mi = 0; mi < 4; mi++) {
        int rr = bm + mi * 16 + mrow;
        r[mi] = rr < M ? rr : M - 1;
    }

    for (int k0 = 0; k0 < 256; k0 += 32) {
        int k = k0 + kg * 8;
        half8 a[4], b[4];
        #pragma unroll
        for (int mi = 0; mi < 4; mi++)
            a[mi] = *(const half8*)(A + (size_t)r[mi] * 256 + k);
        #pragma unroll
        for (int ni = 0; ni < 4; ni++) {
            int n = ni * 16 + mrow;
            b[ni] = *(const half8*)(Bt + (size_t)n * 256 + k);
        }
        #pragma unroll
        for (int mi = 0; mi < 4; mi++)
            #pragma unroll
            for (int ni = 0; ni < 4; ni++)
                acc[mi][ni] = __builtin_amdgcn_mfma_f32_16x16x32_f16(
                    a[mi], b[ni], acc[mi][ni], 0, 0, 0);
    }

    #pragma unroll
    for (int mi = 0; mi < 4; mi++) {
        #pragma unroll
        for (int ni = 0; ni < 4; ni++) {
            int n = ni * 16 + mrow;
            float bv = bias[n];
            #pragma unroll
            for (int rg = 0; rg < 4; rg++) {
                int row = bm + mi * 16 + kg * 4 + rg;
                if (row < M) {
                    float v = acc[mi][ni][rg] + bv;
                    C[(size_t)row * 64 + n] = (_Float16)v;
                }
            }
        }
    }
}

// ---------------------------------------------------------------------------
// APPNP propagation: one wave per dst node, lane = channel; f16 state
// ---------------------------------------------------------------------------

template <typename OUT>
__global__ __launch_bounds__(256) void k_prop(
    const int* __restrict__ rowptr, const int* __restrict__ csr_src,
    const float* __restrict__ csr_norm, const float* __restrict__ dinv,
    const _Float16* __restrict__ h, const _Float16* __restrict__ cur,
    OUT* __restrict__ nxt, int N)
{
    int node = blockIdx.x * (blockDim.x >> 6) + (threadIdx.x >> 6);
    int lane = threadIdx.x & 63;
    if (node >= N) return;
    float dn = dinv[node];
    float acc = dn * dn * (float)cur[(size_t)node * C_OUT + lane];
    int e = rowptr[node], end = rowptr[node + 1];
    for (; e + 3 < end; e += 4) {
        int s0 = csr_src[e],     s1 = csr_src[e + 1];
        int s2 = csr_src[e + 2], s3 = csr_src[e + 3];
        float w0 = csr_norm[e],     w1 = csr_norm[e + 1];
        float w2 = csr_norm[e + 2], w3 = csr_norm[e + 3];
        float v0 = (float)cur[(size_t)s0 * C_OUT + lane];
        float v1 = (float)cur[(size_t)s1 * C_OUT + lane];
        float v2 = (float)cur[(size_t)s2 * C_OUT + lane];
        float v3 = (float)cur[(size_t)s3 * C_OUT + lane];
        acc += w0 * v0 + w1 * v1 + w2 * v2 + w3 * v3;
    }
    for (; e < end; e++)
        acc += csr_norm[e] * (float)cur[(size_t)csr_src[e] * C_OUT + lane];
    float hv = (float)h[(size_t)node * C_OUT + lane];
    nxt[(size_t)node * C_OUT + lane] = (OUT)((1.0f - ALPHA) * acc + ALPHA * hv);
}

// ---------------------------------------------------------------------------
// log_softmax over 64 classes: one wave per node (in-place f32)
// ---------------------------------------------------------------------------

__global__ void k_logsoftmax(const float* __restrict__ in, float* __restrict__ out, int N) {
    int node = blockIdx.x * (blockDim.x >> 6) + (threadIdx.x >> 6);
    int lane = threadIdx.x & 63;
    if (node >= N) return;
    float v = in[(size_t)node * C_OUT + lane];
    float m = v;
    #pragma unroll
    for (int off = 32; off; off >>= 1) m = fmaxf(m, __shfl_xor(m, off));
    float ex = __expf(v - m);
    float s = ex;
    #pragma unroll
    for (int off = 32; off; off >>= 1) s += __shfl_xor(s, off);
    out[(size_t)node * C_OUT + lane] = v - m - logf(s);
}

// ---------------------------------------------------------------------------
// Launch
// ---------------------------------------------------------------------------

extern "C" void kernel_launch(void* const* d_in, const int* in_sizes, int n_in,
                              void* d_out, int out_size, void* d_ws, size_t ws_size,
                              hipStream_t stream) {
    const float* x  = (const float*)d_in[0];
    const int*   ei = (const int*)d_in[1];
    const float* W1 = (const float*)d_in[2];
    const float* b1 = (const float*)d_in[3];
    const float* W2 = (const float*)d_in[4];
    const float* b2 = (const float*)d_in[5];

    const int N = in_sizes[0] / C_IN;
    const int E = in_sizes[1] / 2;
    const int* src = ei;
    const int* dst = ei + E;

    char* ws = (char*)d_ws;
    size_t off = 0;
    auto alloc = [&](size_t bytes) -> void* {
        void* p = ws + off;
        off += (bytes + 255) & ~(size_t)255;
        return p;
    };

    int nb = (N + SCAN_CHUNK - 1) / SCAN_CHUNK;

    int*       counts   = (int*)      alloc((size_t)4 * N);
    int*       rowptr   = (int*)      alloc((size_t)4 * (N + 1));
    int*       cursor   = (int*)      alloc((size_t)4 * N);
    float*     dinv     = (float*)    alloc((size_t)4 * N);
    int*       bsum     = (int*)      alloc((size_t)4 * (nb + 1));
    int*       csr_src  = (int*)      alloc((size_t)4 * E);
    float*     csr_norm = (float*)    alloc((size_t)4 * E);
    _Float16*  W1t      = (_Float16*) alloc((size_t)2 * C_IN * C_HID);
    _Float16*  W2t      = (_Float16*) alloc((size_t)2 * C_HID * C_OUT);
    _Float16*  hmid     = (_Float16*) alloc((size_t)2 * N * C_HID);
    _Float16*  h        = (_Float16*) alloc((size_t)2 * N * C_OUT);
    _Float16*  buf0     = (_Float16*) alloc((size_t)2 * N * C_OUT);
    _Float16*  buf1     = (_Float16*) alloc((size_t)2 * N * C_OUT);

    // --- graph preprocessing ---
    hipMemsetAsync(counts, 0, (size_t)4 * N, stream);
    k_count<<<(E + 255) / 256, 256, 0, stream>>>(dst, E, counts);
    k_dinv<<<(N + 255) / 256, 256, 0, stream>>>(counts, dinv, N);
    k_scan1<<<nb, 256, 0, stream>>>(counts, N, bsum);
    k_scan2<<<1, 64, 0, stream>>>(bsum, nb, E, rowptr, N);
    k_scan3<<<nb, 256, 0, stream>>>(counts, N, bsum, rowptr);
    hipMemcpyAsync(cursor, rowptr, (size_t)4 * N, hipMemcpyDeviceToDevice, stream);
    k_fill<<<(E + 255) / 256, 256, 0, stream>>>(src, dst, E, dinv, cursor, csr_src, csr_norm);

    // --- weight conversion + MLP (f16 MFMA) ---
    k_w1t<<<(C_IN * C_HID) / 256, 256, 0, stream>>>(W1, W1t);
    k_w2t<<<(C_HID * C_OUT) / 256, 256, 0, stream>>>(W2, W2t);
    k_mlp1<<<(N + 63) / 64, 256, 0, stream>>>(x, W1t, b1, hmid, N);
    k_mlp2<<<(N + 255) / 256, 256, 0, stream>>>(hmid, W2t, b2, h, N);

    // --- propagation (ping-pong f16; last iter writes f32 d_out) ---
    int pgrid = (N + 3) / 4;
    const _Float16* cur = h;
    for (int it = 0; it < K_STEPS - 1; ++it) {
        _Float16* nxt = (it & 1) ? buf1 : buf0;
        k_prop<_Float16><<<pgrid, 256, 0, stream>>>(rowptr, csr_src, csr_norm, dinv, h, cur, nxt, N);
        cur = nxt;
    }
    k_prop<float><<<pgrid, 256, 0, stream>>>(rowptr, csr_src, csr_norm, dinv, h, cur, (float*)d_out, N);

    // --- log_softmax (in-place on d_out) ---
    k_logsoftmax<<<pgrid, 256, 0, stream>>>((const float*)d_out, (float*)d_out, N);
}